// Round 1
// baseline (294.174 us; speedup 1.0000x reference)
//
#include <hip/hip_runtime.h>
#include <math.h>

#define B_TOT 4096
#define B_HALF 2048

// ws layout (float offsets)
#define ZT_OFF     0          // 4096*64
#define S_OFF      262144     // 4096
#define E_OFF      266240     // 4096
#define STATS_OFF  270336     // 2 groups * 66 (m, E, T[64])
#define PRED_OFF   270592     // 4096*128
#define PART_OFF   794880     // 4096*8*2 (per-chunk m,s)
#define ROWVAL_OFF 860416     // 4096

// ---------------------------------------------------------------------------
// K1: zt = relu(zw @ lin_w.T + lin_b)  [B,64]; s = tanh(zt@a1w.T+a1b)@a2w.T+a2b
// 4 rows per block, one 64-lane wave per row.
// ---------------------------------------------------------------------------
__global__ void k_zt_s(const float* __restrict__ zw0, const float* __restrict__ zw1,
                       const float* __restrict__ lin0_w, const float* __restrict__ lin0_b,
                       const float* __restrict__ lin1_w, const float* __restrict__ lin1_b,
                       const float* __restrict__ a0_1w, const float* __restrict__ a0_1b,
                       const float* __restrict__ a0_2w, const float* __restrict__ a0_2b,
                       const float* __restrict__ a1_1w, const float* __restrict__ a1_1b,
                       const float* __restrict__ a1_2w, const float* __restrict__ a1_2b,
                       float* __restrict__ ws) {
    __shared__ float zwl[4][128];
    __shared__ float ztl[4][64];
    int tid = threadIdx.x;
    int row = tid >> 6, lane = tid & 63;
    int r = blockIdx.x * 4 + row;
    int g = (r >= B_HALF);
    const float* zwr = g ? (zw1 + (size_t)(r - B_HALF) * 128) : (zw0 + (size_t)r * 128);
    const float* lw = g ? lin1_w : lin0_w;
    const float* lb = g ? lin1_b : lin0_b;
    const float* w1 = g ? a1_1w : a0_1w;
    const float* b1 = g ? a1_1b : a0_1b;
    const float* w2 = g ? a1_2w : a0_2w;
    const float* b2 = g ? a1_2b : a0_2b;

    zwl[row][lane]      = zwr[lane];
    zwl[row][lane + 64] = zwr[lane + 64];
    __syncthreads();

    float acc = lb[lane];
#pragma unroll 8
    for (int k = 0; k < 128; ++k) acc = fmaf(zwl[row][k], lw[lane * 128 + k], acc);
    float zt = fmaxf(acc, 0.f);
    ws[ZT_OFF + (size_t)r * 64 + lane] = zt;
    ztl[row][lane] = zt;
    __syncthreads();

    float h = 0.f;
    if (lane < 32) {
        float a = b1[lane];
#pragma unroll 8
        for (int k = 0; k < 64; ++k) a = fmaf(ztl[row][k], w1[lane * 64 + k], a);
        h = tanhf(a) * w2[lane];
    }
#pragma unroll
    for (int off = 32; off > 0; off >>= 1) h += __shfl_down(h, off);
    if (lane == 0) ws[S_OFF + r] = h + b2[0];
}

// ---------------------------------------------------------------------------
// K2: per group g: m = max(s), e_r = exp(s_r - m), E = sum e, T[64] = sum e_r*zt_r
// grid = 2 blocks of 512 threads.
// ---------------------------------------------------------------------------
__global__ void k_stats(float* __restrict__ ws) {
    __shared__ float red[512];
    __shared__ float el[B_HALF];
    __shared__ float tl[8][64];
    int g = blockIdx.x, tid = threadIdx.x;
    const float* sg = ws + S_OFF + g * B_HALF;

    float m = -INFINITY;
    for (int r = tid; r < B_HALF; r += 512) m = fmaxf(m, sg[r]);
    red[tid] = m;
    __syncthreads();
    for (int o = 256; o > 0; o >>= 1) {
        if (tid < o) red[tid] = fmaxf(red[tid], red[tid + o]);
        __syncthreads();
    }
    m = red[0];
    __syncthreads();

    float Eloc = 0.f;
    for (int r = tid; r < B_HALF; r += 512) {
        float ev = __expf(sg[r] - m);
        el[r] = ev;
        ws[E_OFF + g * B_HALF + r] = ev;
        Eloc += ev;
    }
    __syncthreads();
    red[tid] = Eloc;
    __syncthreads();
    for (int o = 256; o > 0; o >>= 1) {
        if (tid < o) red[tid] += red[tid + o];
        __syncthreads();
    }
    float E = red[0];

    int sub = tid >> 6, d = tid & 63;
    const float* ztg = ws + ZT_OFF + (size_t)g * B_HALF * 64;
    float t = 0.f;
    for (int r = sub; r < B_HALF; r += 8) t = fmaf(el[r], ztg[(size_t)r * 64 + d], t);
    tl[sub][d] = t;
    __syncthreads();
    if (tid < 64) {
        float tt = 0.f;
#pragma unroll
        for (int q = 0; q < 8; ++q) tt += tl[q][tid];
        ws[STATS_OFF + g * 66 + 2 + tid] = tt;
    }
    if (tid == 0) {
        ws[STATS_OFF + g * 66]     = m;
        ws[STATS_OFF + g * 66 + 1] = E;
    }
}

// ---------------------------------------------------------------------------
// K3: pooled[r] = (T - e_r*zt_r)/(E - e_r); pred[r] = pooled@Ww.T + Wwb + c@Wk.T + Wkb
// 2 rows per block, 128 threads per row (one output each).
// ---------------------------------------------------------------------------
__global__ void k_pred(const float* __restrict__ c,
                       const float* __restrict__ Wk_w, const float* __restrict__ Wk_b,
                       const float* __restrict__ Ww0_w, const float* __restrict__ Ww0_b,
                       const float* __restrict__ Ww1_w, const float* __restrict__ Ww1_b,
                       float* __restrict__ ws) {
    __shared__ float pl[2][64], cl[2][64];
    int tid = threadIdx.x;
    int sub = tid >> 7, t = tid & 127;
    int r = blockIdx.x * 2 + sub;
    int g = (r >= B_HALF);
    float er = ws[E_OFF + r];
    float E = ws[STATS_OFF + g * 66 + 1];
    float inv = 1.f / (E - er);
    if (t < 64)
        pl[sub][t] = (ws[STATS_OFF + g * 66 + 2 + t] - er * ws[ZT_OFF + (size_t)r * 64 + t]) * inv;
    else
        cl[sub][t - 64] = c[(size_t)r * 64 + (t - 64)];
    __syncthreads();

    const float* Ww  = g ? Ww1_w : Ww0_w;
    const float* Wwb = g ? Ww1_b : Ww0_b;
    float v = Wwb[t] + Wk_b[t];
#pragma unroll 8
    for (int h = 0; h < 64; ++h) v = fmaf(pl[sub][h], Ww[t * 64 + h], v);
#pragma unroll 8
    for (int k = 0; k < 64; ++k) v = fmaf(cl[sub][k], Wk_w[t * 64 + k], v);
    ws[PRED_OFF + (size_t)r * 128 + t] = v;
}

// ---------------------------------------------------------------------------
// K4: fused total = zw @ pred.T with online per-row (max, sumexp) over j.
// Grid: (8 j-chunks of 512) x (64 i-tiles of 64). Block 256 threads.
// 64x64 tile, 4x4 register tile/thread, XOR-swizzled float4 LDS (no pad,
// 64KB total, 2-way max conflicts which are free).
// ---------------------------------------------------------------------------
__global__ __launch_bounds__(256, 2)
void k_main(const float* __restrict__ zw0, const float* __restrict__ zw1,
            float* __restrict__ ws) {
    __shared__ float4 zwT[64][32];
    __shared__ float4 predT[64][32];
    int tid = threadIdx.x;
    int cx = blockIdx.x;            // j-chunk 0..7
    int i0 = blockIdx.y * 64;

    // stage zw tile (swizzled: col c stored at c ^ (row&7))
    for (int idx = tid; idx < 2048; idx += 256) {
        int row = idx >> 5, cc = idx & 31;
        int gi = i0 + row;
        const float* zr = (gi < B_HALF) ? (zw0 + (size_t)gi * 128)
                                        : (zw1 + (size_t)(gi - B_HALF) * 128);
        zwT[row][cc ^ (row & 7)] = ((const float4*)zr)[cc];
    }

    int tx = tid & 15, ty = tid >> 4;
    float m[4], s[4];
#pragma unroll
    for (int a = 0; a < 4; ++a) { m[a] = -INFINITY; s[a] = 0.f; }

    const float4* pred4 = (const float4*)(ws + PRED_OFF);

    for (int jt = 0; jt < 8; ++jt) {
        int j0 = cx * 512 + jt * 64;
        __syncthreads();  // previous tile fully consumed (and zw staging visible)
        for (int idx = tid; idx < 2048; idx += 256) {
            int row = idx >> 5, cc = idx & 31;
            predT[row][cc ^ (row & 7)] = pred4[(size_t)(j0 + row) * 32 + cc];
        }
        __syncthreads();

        float acc[4][4] = {{0.f}};
#pragma unroll 4
        for (int k4 = 0; k4 < 32; ++k4) {
            float4 za[4], pb[4];
#pragma unroll
            for (int a = 0; a < 4; ++a) za[a] = zwT[tx + 16 * a][k4 ^ (tx & 7)];
#pragma unroll
            for (int b = 0; b < 4; ++b) pb[b] = predT[ty + 16 * b][k4 ^ (ty & 7)];
#pragma unroll
            for (int a = 0; a < 4; ++a)
#pragma unroll
                for (int b = 0; b < 4; ++b) {
                    acc[a][b] = fmaf(za[a].x, pb[b].x, acc[a][b]);
                    acc[a][b] = fmaf(za[a].y, pb[b].y, acc[a][b]);
                    acc[a][b] = fmaf(za[a].z, pb[b].z, acc[a][b]);
                    acc[a][b] = fmaf(za[a].w, pb[b].w, acc[a][b]);
                }
        }
        // online logsumexp update per i-row
#pragma unroll
        for (int a = 0; a < 4; ++a) {
            float vm = fmaxf(fmaxf(acc[a][0], acc[a][1]), fmaxf(acc[a][2], acc[a][3]));
            float mn = fmaxf(m[a], vm);
            float add = __expf(acc[a][0] - mn) + __expf(acc[a][1] - mn) +
                        __expf(acc[a][2] - mn) + __expf(acc[a][3] - mn);
            s[a] = s[a] * __expf(m[a] - mn) + add;
            m[a] = mn;
        }
    }
    __syncthreads();
    // reduce 16 partials per i-row via LDS overlay on predT
    float* red = (float*)predT;
#pragma unroll
    for (int a = 0; a < 4; ++a) {
        int il = tx + 16 * a;
        red[il * 32 + ty * 2]     = m[a];
        red[il * 32 + ty * 2 + 1] = s[a];
    }
    __syncthreads();
    if (tid < 64) {
        float M = -INFINITY;
#pragma unroll
        for (int q = 0; q < 16; ++q) M = fmaxf(M, red[tid * 32 + q * 2]);
        float S = 0.f;
#pragma unroll
        for (int q = 0; q < 16; ++q)
            S += red[tid * 32 + q * 2 + 1] * __expf(red[tid * 32 + q * 2] - M);
        int gi = i0 + tid;
        ws[PART_OFF + (size_t)gi * 16 + cx * 2]     = M;
        ws[PART_OFF + (size_t)gi * 16 + cx * 2 + 1] = S;
    }
}

// ---------------------------------------------------------------------------
// K5: per row: merge 8 chunk partials -> lse; diag = dot(zw[r], pred[r]);
// rowval = diag - lse.  4 rows/block, one wave per row.
// ---------------------------------------------------------------------------
__global__ void k_row(const float* __restrict__ zw0, const float* __restrict__ zw1,
                      float* __restrict__ ws) {
    int tid = threadIdx.x;
    int sub = tid >> 6, lane = tid & 63;
    int r = blockIdx.x * 4 + sub;
    const float* zr = (r < B_HALF) ? (zw0 + (size_t)r * 128)
                                   : (zw1 + (size_t)(r - B_HALF) * 128);
    const float* pr = ws + PRED_OFF + (size_t)r * 128;
    float p = zr[lane] * pr[lane] + zr[lane + 64] * pr[lane + 64];
#pragma unroll
    for (int off = 32; off > 0; off >>= 1) p += __shfl_down(p, off);
    if (lane == 0) {
        float M = -INFINITY;
#pragma unroll
        for (int q = 0; q < 8; ++q) M = fmaxf(M, ws[PART_OFF + (size_t)r * 16 + q * 2]);
        float S = 0.f;
#pragma unroll
        for (int q = 0; q < 8; ++q)
            S += ws[PART_OFF + (size_t)r * 16 + q * 2 + 1] *
                 __expf(ws[PART_OFF + (size_t)r * 16 + q * 2] - M);
        ws[ROWVAL_OFF + r] = p - (M + logf(S));
    }
}

// ---------------------------------------------------------------------------
// K6: out = -sum(rowval)/B
// ---------------------------------------------------------------------------
__global__ void k_final(const float* __restrict__ ws, float* __restrict__ out) {
    __shared__ float red[1024];
    int tid = threadIdx.x;
    float a = 0.f;
    for (int r = tid; r < B_TOT; r += 1024) a += ws[ROWVAL_OFF + r];
    red[tid] = a;
    __syncthreads();
    for (int o = 512; o > 0; o >>= 1) {
        if (tid < o) red[tid] += red[tid + o];
        __syncthreads();
    }
    if (tid == 0) out[0] = -red[0] / (float)B_TOT;
}

extern "C" void kernel_launch(void* const* d_in, const int* in_sizes, int n_in,
                              void* d_out, int out_size, void* d_ws, size_t ws_size,
                              hipStream_t stream) {
    const float* zw_0   = (const float*)d_in[0];
    const float* zw_1   = (const float*)d_in[1];
    const float* c      = (const float*)d_in[2];
    const float* Wk_w   = (const float*)d_in[3];
    const float* Wk_b   = (const float*)d_in[4];
    const float* Ww0_w  = (const float*)d_in[5];
    const float* Ww0_b  = (const float*)d_in[6];
    const float* Ww1_w  = (const float*)d_in[7];
    const float* Ww1_b  = (const float*)d_in[8];
    const float* lin0_w = (const float*)d_in[9];
    const float* lin0_b = (const float*)d_in[10];
    const float* lin1_w = (const float*)d_in[11];
    const float* lin1_b = (const float*)d_in[12];
    const float* a0_1w  = (const float*)d_in[13];
    const float* a0_1b  = (const float*)d_in[14];
    const float* a0_2w  = (const float*)d_in[15];
    const float* a0_2b  = (const float*)d_in[16];
    const float* a1_1w  = (const float*)d_in[17];
    const float* a1_1b  = (const float*)d_in[18];
    const float* a1_2w  = (const float*)d_in[19];
    const float* a1_2b  = (const float*)d_in[20];
    float* ws  = (float*)d_ws;
    float* out = (float*)d_out;

    k_zt_s<<<1024, 256, 0, stream>>>(zw_0, zw_1, lin0_w, lin0_b, lin1_w, lin1_b,
                                     a0_1w, a0_1b, a0_2w, a0_2b,
                                     a1_1w, a1_1b, a1_2w, a1_2b, ws);
    k_stats<<<2, 512, 0, stream>>>(ws);
    k_pred<<<2048, 256, 0, stream>>>(c, Wk_w, Wk_b, Ww0_w, Ww0_b, Ww1_w, Ww1_b, ws);
    k_main<<<dim3(8, 64), 256, 0, stream>>>(zw_0, zw_1, ws);
    k_row<<<1024, 256, 0, stream>>>(zw_0, zw_1, ws);
    k_final<<<1, 1024, 0, stream>>>(ws, out);
}

// Round 2
// 172.392 us; speedup vs baseline: 1.7064x; 1.7064x over previous
//
#include <hip/hip_runtime.h>
#include <math.h>

#define B_TOT 4096
#define B_HALF 2048

// ws float offsets. Region [0..524288) holds ZT/S/STATS for dispatches 1-3,
// then is REUSED as PART (4096 rows x 64 chunks x float2) by k_main/k_row.
#define ZT_OFF     0          // 4096*64
#define S_OFF      262144     // 4096
#define STATS_OFF  266240     // 2 groups * 66 (m, E, T[64])
#define ZWB_OFF    524288     // bf16 4096*128 (as 262144 floats)
#define PREDB_OFF  786432     // bf16 4096*128 (as 262144 floats)
#define ROWVAL_OFF 1048576    // 4096

typedef __bf16 bf16x8 __attribute__((ext_vector_type(8)));
typedef float  f32x4  __attribute__((ext_vector_type(4)));

__device__ __forceinline__ unsigned short f2bf(float f) {
    unsigned u = __float_as_uint(f);
    u = u + 0x7fffu + ((u >> 16) & 1u);   // round-to-nearest-even
    return (unsigned short)(u >> 16);
}
__device__ __forceinline__ float bf2f(unsigned short h) {
    return __uint_as_float(((unsigned)h) << 16);
}

// ---------------------------------------------------------------------------
// K1: zt = relu(zw @ lin_w.T + lb)  [16 rows/block]; s = attention score.
// Weights staged to LDS in natural layout; thread o reads its weight row as
// float4 (phase-wise conflict-bounded), row-vectors broadcast. Also emits
// bf16 cast of zw into ws (ZWB) for the MFMA main kernel.
// ---------------------------------------------------------------------------
__global__ __launch_bounds__(256)
void k_zt_s(const float* __restrict__ zw0, const float* __restrict__ zw1,
            const float* __restrict__ lin0_w, const float* __restrict__ lin0_b,
            const float* __restrict__ lin1_w, const float* __restrict__ lin1_b,
            const float* __restrict__ a0_1w, const float* __restrict__ a0_1b,
            const float* __restrict__ a0_2w, const float* __restrict__ a0_2b,
            const float* __restrict__ a1_1w, const float* __restrict__ a1_1b,
            const float* __restrict__ a1_2w, const float* __restrict__ a1_2b,
            float* __restrict__ ws) {
    __shared__ float lws[64 * 132];   // lin_w [64 out][128 k], stride 132
    __shared__ float zws[16 * 132];   // zw rows [16][128]
    __shared__ float ztl[16 * 68];    // zt rows [16][64]
    __shared__ float a1s[32 * 68];    // a1 weights [32 out][64 k]
    int tid = threadIdx.x;
    int base = blockIdx.x * 16;
    int g = (base >= B_HALF);
    const float* lw = g ? lin1_w : lin0_w;
    const float* lb = g ? lin1_b : lin0_b;
    const float* w1 = g ? a1_1w : a0_1w;
    const float* b1 = g ? a1_1b : a0_1b;
    const float* w2 = g ? a1_2w : a0_2w;
    const float* b2 = g ? a1_2b : a0_2b;
    unsigned short* zwb = (unsigned short*)(ws + ZWB_OFF);

    // stage lin_w: 8192 floats = 2048 float4
    const float4* lw4 = (const float4*)lw;
    for (int i = tid; i < 2048; i += 256) {
        int o = i >> 5, k4 = i & 31;
        ((float4*)(lws + o * 132))[k4] = lw4[i];
    }
    // stage zw rows + write bf16 copy
    for (int i = tid; i < 512; i += 256) {
        int r = i >> 5, k4 = i & 31;
        int gi = base + r;
        const float* zr = (gi < B_HALF) ? (zw0 + (size_t)gi * 128)
                                        : (zw1 + (size_t)(gi - B_HALF) * 128);
        float4 v = ((const float4*)zr)[k4];
        ((float4*)(zws + r * 132))[k4] = v;
        uint2 p;
        p.x = (unsigned)f2bf(v.x) | ((unsigned)f2bf(v.y) << 16);
        p.y = (unsigned)f2bf(v.z) | ((unsigned)f2bf(v.w) << 16);
        ((uint2*)(zwb + (size_t)gi * 128))[k4] = p;
    }
    // stage a1w: 2048 floats = 512 float4
    const float4* w14 = (const float4*)w1;
    for (int i = tid; i < 512; i += 256) {
        int o = i >> 4, k4 = i & 15;
        ((float4*)(a1s + o * 68))[k4] = w14[i];
    }
    __syncthreads();

    // zt: out o = tid&63, rows rgrp, rgrp+4, rgrp+8, rgrp+12
    int o = tid & 63, rgrp = tid >> 6;
    {
        float bias = lb[o];
        float acc[4] = {bias, bias, bias, bias};
        const float4* wrow = (const float4*)(lws + o * 132);
        const float4* zr0 = (const float4*)(zws + (rgrp + 0) * 132);
        const float4* zr1 = (const float4*)(zws + (rgrp + 4) * 132);
        const float4* zr2 = (const float4*)(zws + (rgrp + 8) * 132);
        const float4* zr3 = (const float4*)(zws + (rgrp + 12) * 132);
#pragma unroll 4
        for (int k4 = 0; k4 < 32; ++k4) {
            float4 wv = wrow[k4];
            float4 z0 = zr0[k4], z1 = zr1[k4], z2 = zr2[k4], z3 = zr3[k4];
            acc[0] = fmaf(wv.x, z0.x, fmaf(wv.y, z0.y, fmaf(wv.z, z0.z, fmaf(wv.w, z0.w, acc[0]))));
            acc[1] = fmaf(wv.x, z1.x, fmaf(wv.y, z1.y, fmaf(wv.z, z1.z, fmaf(wv.w, z1.w, acc[1]))));
            acc[2] = fmaf(wv.x, z2.x, fmaf(wv.y, z2.y, fmaf(wv.z, z2.z, fmaf(wv.w, z2.w, acc[2]))));
            acc[3] = fmaf(wv.x, z3.x, fmaf(wv.y, z3.y, fmaf(wv.z, z3.z, fmaf(wv.w, z3.w, acc[3]))));
        }
#pragma unroll
        for (int rr = 0; rr < 4; ++rr) {
            int row = rgrp + rr * 4;
            float zt = fmaxf(acc[rr], 0.f);
            ztl[row * 68 + o] = zt;
            ws[ZT_OFF + (size_t)(base + row) * 64 + o] = zt;
        }
    }
    __syncthreads();

    // attention score: o2 = tid&31, rows r2 and r2+8
    int o2 = tid & 31, r2 = tid >> 5;
    const float4* arow = (const float4*)(a1s + o2 * 68);
#pragma unroll
    for (int rpass = 0; rpass < 2; ++rpass) {
        int row = r2 + rpass * 8;
        float a = b1[o2];
        const float4* zt4 = (const float4*)(ztl + row * 68);
#pragma unroll 4
        for (int k4 = 0; k4 < 16; ++k4) {
            float4 wv = arow[k4];
            float4 zv = zt4[k4];
            a = fmaf(wv.x, zv.x, fmaf(wv.y, zv.y, fmaf(wv.z, zv.z, fmaf(wv.w, zv.w, a))));
        }
        float h = tanhf(a) * w2[o2];
#pragma unroll
        for (int mask = 16; mask > 0; mask >>= 1) h += __shfl_xor(h, mask);
        if (o2 == 0) ws[S_OFF + base + row] = h + b2[0];
    }
}

// ---------------------------------------------------------------------------
// K2: per group: m = max(s), E = sum exp(s-m), T[64] = sum exp(s_r-m)*zt_r.
// ---------------------------------------------------------------------------
__global__ __launch_bounds__(1024)
void k_stats(float* __restrict__ ws) {
    __shared__ float red[1024];
    __shared__ float el[B_HALF];
    __shared__ float tl[16 * 64];
    int gg = blockIdx.x, tid = threadIdx.x;
    const float* sg = ws + S_OFF + gg * B_HALF;

    float m = -INFINITY;
    for (int r = tid; r < B_HALF; r += 1024) m = fmaxf(m, sg[r]);
    red[tid] = m;
    __syncthreads();
    for (int o = 512; o > 0; o >>= 1) {
        if (tid < o) red[tid] = fmaxf(red[tid], red[tid + o]);
        __syncthreads();
    }
    m = red[0];
    __syncthreads();

    float Eloc = 0.f;
    for (int r = tid; r < B_HALF; r += 1024) {
        float ev = __expf(sg[r] - m);
        el[r] = ev;
        Eloc += ev;
    }
    red[tid] = Eloc;
    __syncthreads();
    for (int o = 512; o > 0; o >>= 1) {
        if (tid < o) red[tid] += red[tid + o];
        __syncthreads();
    }
    float E = red[0];

    int sub = tid >> 6, d = tid & 63;
    const float* ztg = ws + ZT_OFF + (size_t)gg * B_HALF * 64;
    float t = 0.f;
    for (int r = sub; r < B_HALF; r += 16) t = fmaf(el[r], ztg[(size_t)r * 64 + d], t);
    tl[sub * 64 + d] = t;
    __syncthreads();
    if (tid < 64) {
        float tt = 0.f;
#pragma unroll
        for (int q = 0; q < 16; ++q) tt += tl[q * 64 + tid];
        ws[STATS_OFF + gg * 66 + 2 + tid] = tt;
    }
    if (tid == 0) {
        ws[STATS_OFF + gg * 66]     = m;
        ws[STATS_OFF + gg * 66 + 1] = E;
    }
}

// ---------------------------------------------------------------------------
// K3: pooled[r] = (T - e_r*zt_r)/(E - e_r); pred[r] = pooled@Ww.T+Wwb + c@Wk.T+Wkb
// 16 rows/block, output only bf16 (PREDB). Weights in LDS natural layout.
// ---------------------------------------------------------------------------
__global__ __launch_bounds__(256)
void k_pred(const float* __restrict__ c,
            const float* __restrict__ Wk_w, const float* __restrict__ Wk_b,
            const float* __restrict__ Ww0_w, const float* __restrict__ Ww0_b,
            const float* __restrict__ Ww1_w, const float* __restrict__ Ww1_b,
            float* __restrict__ ws) {
    __shared__ float Wws[128 * 68];
    __shared__ float Wks[128 * 68];
    __shared__ float pl[16 * 68];
    __shared__ float cl[16 * 68];
    __shared__ float er_l[16], inv_l[16];
    int tid = threadIdx.x;
    int base = blockIdx.x * 16;
    int g = (base >= B_HALF);
    const float* Ww  = g ? Ww1_w : Ww0_w;
    const float* Wwb = g ? Ww1_b : Ww0_b;
    unsigned short* predb = (unsigned short*)(ws + PREDB_OFF);

    const float4* Ww4 = (const float4*)Ww;
    const float4* Wk4 = (const float4*)Wk_w;
    for (int i = tid; i < 2048; i += 256) {
        int o = i >> 4, k4 = i & 15;
        ((float4*)(Wws + o * 68))[k4] = Ww4[i];
        ((float4*)(Wks + o * 68))[k4] = Wk4[i];
    }
    for (int i = tid; i < 256; i += 256) {
        int r = i >> 4, k4 = i & 15;
        ((float4*)(cl + r * 68))[k4] = ((const float4*)(c + (size_t)(base + r) * 64))[k4];
    }
    if (tid < 16) {
        float m = ws[STATS_OFF + g * 66];
        float E = ws[STATS_OFF + g * 66 + 1];
        float er = __expf(ws[S_OFF + base + tid] - m);
        er_l[tid] = er;
        inv_l[tid] = 1.f / (E - er);
    }
    __syncthreads();
    for (int i = tid; i < 1024; i += 256) {
        int r = i >> 6, k = i & 63;
        float T = ws[STATS_OFF + g * 66 + 2 + k];
        float zt = ws[ZT_OFF + (size_t)(base + r) * 64 + k];
        pl[r * 68 + k] = (T - er_l[r] * zt) * inv_l[r];
    }
    __syncthreads();

    int o = tid & 127, rsel = tid >> 7;   // 8 rows per thread: rsel, rsel+2, ...
    float bias = Wwb[o] + Wk_b[o];
    float acc[8] = {bias, bias, bias, bias, bias, bias, bias, bias};
    const float4* wrow = (const float4*)(Wws + o * 68);
    const float4* krow = (const float4*)(Wks + o * 68);
#pragma unroll 4
    for (int k4 = 0; k4 < 16; ++k4) {
        float4 wv = wrow[k4];
#pragma unroll
        for (int j = 0; j < 8; ++j) {
            float4 pv = ((const float4*)(pl + (rsel + j * 2) * 68))[k4];
            acc[j] = fmaf(wv.x, pv.x, fmaf(wv.y, pv.y, fmaf(wv.z, pv.z, fmaf(wv.w, pv.w, acc[j]))));
        }
    }
#pragma unroll 4
    for (int k4 = 0; k4 < 16; ++k4) {
        float4 kv = krow[k4];
#pragma unroll
        for (int j = 0; j < 8; ++j) {
            float4 cv = ((const float4*)(cl + (rsel + j * 2) * 68))[k4];
            acc[j] = fmaf(kv.x, cv.x, fmaf(kv.y, cv.y, fmaf(kv.z, cv.z, fmaf(kv.w, cv.w, acc[j]))));
        }
    }
#pragma unroll
    for (int j = 0; j < 8; ++j) {
        int gi = base + rsel + j * 2;
        predb[(size_t)gi * 128 + o] = f2bf(acc[j]);
    }
}

// ---------------------------------------------------------------------------
// K4: logits tile via MFMA bf16: D = zw @ pred^T, 64x64 per block (4 waves,
// each wave 16 rows x 64 cols). Per-tile rowwise (max, sumexp) partials to PART.
// ---------------------------------------------------------------------------
__global__ __launch_bounds__(256)
void k_main(float* __restrict__ ws) {
    __shared__ unsigned short zs[64 * 136];  // 64 rows x 128 bf16, stride 136 (272B)
    __shared__ unsigned short ps[64 * 136];
    int tid = threadIdx.x;
    int jx = blockIdx.x;            // j-chunk 0..63
    int i0 = blockIdx.y * 64, j0 = jx * 64;
    const unsigned short* zwb   = (const unsigned short*)(ws + ZWB_OFF);
    const unsigned short* predb = (const unsigned short*)(ws + PREDB_OFF);

    for (int i = tid; i < 1024; i += 256) {
        int r = i >> 4, gq = i & 15;
        ((float4*)(zs + r * 136))[gq] = ((const float4*)(zwb + (size_t)(i0 + r) * 128))[gq];
        ((float4*)(ps + r * 136))[gq] = ((const float4*)(predb + (size_t)(j0 + r) * 128))[gq];
    }
    __syncthreads();

    int lane = tid & 63, w = tid >> 6;
    int m16 = lane & 15, quad = lane >> 4;

    bf16x8 af[4];
#pragma unroll
    for (int kk = 0; kk < 4; ++kk)
        af[kk] = *((const bf16x8*)(zs + (w * 16 + m16) * 136 + kk * 32 + quad * 8));

    f32x4 acc[4];
#pragma unroll
    for (int b = 0; b < 4; ++b) acc[b] = (f32x4){0.f, 0.f, 0.f, 0.f};

#pragma unroll
    for (int b = 0; b < 4; ++b) {
#pragma unroll
        for (int kk = 0; kk < 4; ++kk) {
            bf16x8 bf = *((const bf16x8*)(ps + (b * 16 + m16) * 136 + kk * 32 + quad * 8));
            acc[b] = __builtin_amdgcn_mfma_f32_16x16x32_bf16(af[kk], bf, acc[b], 0, 0, 0);
        }
    }

    // epilogue: lane holds D[quad*4+r][b*16 + m16] for r=0..3
    float2* part = (float2*)ws;   // PART overlays region A
#pragma unroll
    for (int r = 0; r < 4; ++r) {
        float vm = fmaxf(fmaxf(acc[0][r], acc[1][r]), fmaxf(acc[2][r], acc[3][r]));
#pragma unroll
        for (int mask = 8; mask > 0; mask >>= 1) vm = fmaxf(vm, __shfl_xor(vm, mask));
        float se = __expf(acc[0][r] - vm) + __expf(acc[1][r] - vm) +
                   __expf(acc[2][r] - vm) + __expf(acc[3][r] - vm);
#pragma unroll
        for (int mask = 8; mask > 0; mask >>= 1) se += __shfl_xor(se, mask);
        if (m16 == 0) {
            int gi = i0 + w * 16 + quad * 4 + r;
            part[(size_t)gi * 64 + jx] = make_float2(vm, se);
        }
    }
}

// ---------------------------------------------------------------------------
// K5: per row: merge 64 chunk partials -> lse; diag = dot(zw[r], pred[r]);
// rowval = diag - lse. One wave per row.
// ---------------------------------------------------------------------------
__global__ __launch_bounds__(256)
void k_row(const float* __restrict__ zw0, const float* __restrict__ zw1,
           float* __restrict__ ws) {
    int tid = threadIdx.x;
    int sub = tid >> 6, lane = tid & 63;
    int r = blockIdx.x * 4 + sub;
    const float2* part = (const float2*)ws;
    const unsigned short* predb = (const unsigned short*)(ws + PREDB_OFF);

    float2 p2 = part[(size_t)r * 64 + lane];
    float M = p2.x, S = p2.y;
#pragma unroll
    for (int mask = 32; mask > 0; mask >>= 1) M = fmaxf(M, __shfl_xor(M, mask));
    S = S * __expf(p2.x - M);
#pragma unroll
    for (int mask = 32; mask > 0; mask >>= 1) S += __shfl_xor(S, mask);

    const float* zr = (r < B_HALF) ? (zw0 + (size_t)r * 128)
                                   : (zw1 + (size_t)(r - B_HALF) * 128);
    const unsigned short* pr = predb + (size_t)r * 128;
    float d = zr[lane] * bf2f(pr[lane]) + zr[lane + 64] * bf2f(pr[lane + 64]);
#pragma unroll
    for (int mask = 32; mask > 0; mask >>= 1) d += __shfl_xor(d, mask);

    if (lane == 0) ws[ROWVAL_OFF + r] = d - (M + logf(S));
}

// ---------------------------------------------------------------------------
// K6: out = -sum(rowval)/B
// ---------------------------------------------------------------------------
__global__ __launch_bounds__(1024)
void k_final(const float* __restrict__ ws, float* __restrict__ out) {
    __shared__ float red[1024];
    int tid = threadIdx.x;
    float a = 0.f;
    for (int r = tid; r < B_TOT; r += 1024) a += ws[ROWVAL_OFF + r];
    red[tid] = a;
    __syncthreads();
    for (int o = 512; o > 0; o >>= 1) {
        if (tid < o) red[tid] += red[tid + o];
        __syncthreads();
    }
    if (tid == 0) out[0] = -red[0] / (float)B_TOT;
}

extern "C" void kernel_launch(void* const* d_in, const int* in_sizes, int n_in,
                              void* d_out, int out_size, void* d_ws, size_t ws_size,
                              hipStream_t stream) {
    const float* zw_0   = (const float*)d_in[0];
    const float* zw_1   = (const float*)d_in[1];
    const float* c      = (const float*)d_in[2];
    const float* Wk_w   = (const float*)d_in[3];
    const float* Wk_b   = (const float*)d_in[4];
    const float* Ww0_w  = (const float*)d_in[5];
    const float* Ww0_b  = (const float*)d_in[6];
    const float* Ww1_w  = (const float*)d_in[7];
    const float* Ww1_b  = (const float*)d_in[8];
    const float* lin0_w = (const float*)d_in[9];
    const float* lin0_b = (const float*)d_in[10];
    const float* lin1_w = (const float*)d_in[11];
    const float* lin1_b = (const float*)d_in[12];
    const float* a0_1w  = (const float*)d_in[13];
    const float* a0_1b  = (const float*)d_in[14];
    const float* a0_2w  = (const float*)d_in[15];
    const float* a0_2b  = (const float*)d_in[16];
    const float* a1_1w  = (const float*)d_in[17];
    const float* a1_1b  = (const float*)d_in[18];
    const float* a1_2w  = (const float*)d_in[19];
    const float* a1_2b  = (const float*)d_in[20];
    float* ws  = (float*)d_ws;
    float* out = (float*)d_out;

    k_zt_s<<<256, 256, 0, stream>>>(zw_0, zw_1, lin0_w, lin0_b, lin1_w, lin1_b,
                                    a0_1w, a0_1b, a0_2w, a0_2b,
                                    a1_1w, a1_1b, a1_2w, a1_2b, ws);
    k_stats<<<2, 1024, 0, stream>>>(ws);
    k_pred<<<256, 256, 0, stream>>>(c, Wk_w, Wk_b, Ww0_w, Ww0_b, Ww1_w, Ww1_b, ws);
    k_main<<<dim3(64, 64), 256, 0, stream>>>(ws);
    k_row<<<1024, 256, 0, stream>>>(zw_0, zw_1, ws);
    k_final<<<1, 1024, 0, stream>>>(ws, out);
}